// Round 1
// baseline (70.510 us; speedup 1.0000x reference)
//
#include <hip/hip_runtime.h>

// GMP forward: out[b,j] = sum_i xc[j+i-7] * ( W0[i] + sum_{m,d} W3[i,m,d]*|xc[j+i+m-14]|^(d+1) )
// B=64, T=16384, M=8, K=3. Weights real -> coefficient per tap is real.

#define B_SZ 64
#define T_SZ 16384
#define M_SZ 8
#define K_SZ 3
#define CHUNK 256
#define HALO 14              // 2*(M-1)
#define WIN (CHUNK + HALO)   // 270

__global__ __launch_bounds__(256) void gmp_kernel(const float* __restrict__ x,
                                                  const float* __restrict__ W,
                                                  float* __restrict__ out) {
    __shared__ float xre[WIN], xim[WIN], a1[WIN], a2[WIN], a3[WIN];
    const int tid   = threadIdx.x;
    const int chunk = blockIdx.x & 63;   // T/CHUNK = 64 chunks per row
    const int b     = blockIdx.x >> 6;
    const int j0    = chunk * CHUNK;

    // Phase 1: stage window [j0-14, j0+256) of row b; zero-pad g<0.
    for (int q = tid; q < WIN; q += 256) {
        const int g = j0 - HALO + q;
        float re = 0.f, im = 0.f;
        if (g >= 0) {
            const float2 v = ((const float2*)x)[(size_t)b * T_SZ + g];
            re = v.x; im = v.y;
        }
        const float s2 = fmaf(re, re, im * im);
        const float s1 = sqrtf(s2);
        xre[q] = re; xim[q] = im;
        a1[q] = s1; a2[q] = s2; a3[q] = s2 * s1;
    }
    __syncthreads();

    // Phase 2: one output per thread.
    float accr = 0.f, acci = 0.f;
#pragma unroll
    for (int i = 0; i < M_SZ; ++i) {
        float c = W[i * 25];             // W0[i]; uniform -> scalar load
#pragma unroll
        for (int m = 0; m < M_SZ; ++m) {
            const int q = tid + i + m;   // amp position j+i+m-14
            const int wb = i * 25 + 1 + m * 3;
            c = fmaf(W[wb + 0], a1[q], c);
            c = fmaf(W[wb + 1], a2[q], c);
            c = fmaf(W[wb + 2], a3[q], c);
        }
        const int qx = tid + i + 7;      // xc position j+i-7
        accr = fmaf(xre[qx], c, accr);
        acci = fmaf(xim[qx], c, acci);
    }

    const int j = j0 + tid;
    ((float2*)out)[(size_t)b * T_SZ + j] = make_float2(accr, acci);
}

extern "C" void kernel_launch(void* const* d_in, const int* in_sizes, int n_in,
                              void* d_out, int out_size, void* d_ws, size_t ws_size,
                              hipStream_t stream) {
    const float* x = (const float*)d_in[0];
    // d_in[1] is h_0 (unused)
    const float* W = (const float*)d_in[2];
    float* out = (float*)d_out;
    const int grid = B_SZ * (T_SZ / CHUNK);  // 4096 blocks
    gmp_kernel<<<dim3(grid), dim3(256), 0, stream>>>(x, W, out);
}

// Round 2
// 68.084 us; speedup vs baseline: 1.0356x; 1.0356x over previous
//
#include <hip/hip_runtime.h>

// GMP forward: out[b,j] = sum_i xc[j+i-7] * ( W0[i] + sum_{m} a*(w1 + a*(w2 + a*w3)) )
// with a = |xc[j+i+m-14]|.  B=64, T=16384, M=8, K=3. Weights real.
// Horner form needs only |xc| in LDS (no a^2, a^3 arrays) -> LDS traffic /3.
// 2 outputs per thread: amp window [2t..2t+15] and x window [2t+7..2t+15] shared.

#define B_SZ 64
#define T_SZ 16384
#define CHUNK 512
#define HALO 14              // 2*(M-1)
#define WIN (CHUNK + HALO)   // 526

__global__ __launch_bounds__(256) void gmp_kernel(const float* __restrict__ x,
                                                  const float* __restrict__ W,
                                                  float* __restrict__ out) {
    __shared__ float2 xs[WIN];   // xc window
    __shared__ float  as[WIN];   // |xc| window
    const int tid   = threadIdx.x;
    const int chunk = blockIdx.x & 31;   // T/CHUNK = 32 chunks per row
    const int b     = blockIdx.x >> 5;
    const int j0    = chunk * CHUNK;

    // Stage window [j0-14, j0+512) of row b; zero-pad g<0.
    for (int q = tid; q < WIN; q += 256) {
        const int g = j0 - HALO + q;
        float2 v = make_float2(0.f, 0.f);
        if (g >= 0) v = ((const float2*)x)[(size_t)b * T_SZ + g];
        xs[q] = v;
        as[q] = sqrtf(fmaf(v.x, v.x, v.y * v.y));
    }
    __syncthreads();

    // Each thread: outputs j = j0 + 2*tid + {0,1}.
    float av[16];
#pragma unroll
    for (int k = 0; k < 16; ++k) av[k] = as[2 * tid + k];
    float2 xv[9];
#pragma unroll
    for (int k = 0; k < 9; ++k) xv[k] = xs[2 * tid + 7 + k];

    float ar0 = 0.f, ai0 = 0.f, ar1 = 0.f, ai1 = 0.f;
#pragma unroll
    for (int i = 0; i < 8; ++i) {
        float c0 = W[i * 25];
        float c1 = c0;
#pragma unroll
        for (int m = 0; m < 8; ++m) {
            const float w1 = W[i * 25 + 1 + m * 3];
            const float w2 = W[i * 25 + 2 + m * 3];
            const float w3 = W[i * 25 + 3 + m * 3];
            const float a0 = av[i + m];
            const float a1 = av[i + m + 1];
            float h0 = fmaf(a0, w3, w2);  h0 = fmaf(a0, h0, w1);  c0 = fmaf(a0, h0, c0);
            float h1 = fmaf(a1, w3, w2);  h1 = fmaf(a1, h1, w1);  c1 = fmaf(a1, h1, c1);
        }
        ar0 = fmaf(xv[i].x,     c0, ar0);
        ai0 = fmaf(xv[i].y,     c0, ai0);
        ar1 = fmaf(xv[i + 1].x, c1, ar1);
        ai1 = fmaf(xv[i + 1].y, c1, ai1);
    }

    // Two consecutive complex outputs -> one 16B store (16B-aligned: 2*tid even).
    float4 o; o.x = ar0; o.y = ai0; o.z = ar1; o.w = ai1;
    ((float4*)out)[((size_t)b * T_SZ + j0) / 2 + tid] = o;
}

extern "C" void kernel_launch(void* const* d_in, const int* in_sizes, int n_in,
                              void* d_out, int out_size, void* d_ws, size_t ws_size,
                              hipStream_t stream) {
    const float* x = (const float*)d_in[0];
    // d_in[1] is h_0 (unused)
    const float* W = (const float*)d_in[2];
    float* out = (float*)d_out;
    const int grid = B_SZ * (T_SZ / CHUNK);  // 2048 blocks
    gmp_kernel<<<dim3(grid), dim3(256), 0, stream>>>(x, W, out);
}

// Round 3
// 68.010 us; speedup vs baseline: 1.0368x; 1.0011x over previous
//
#include <hip/hip_runtime.h>

// GMP forward: out[b,j] = sum_i xc[j+i-7] * ( W0[i] + sum_m a*(w1 + a*(w2 + a*w3)) ),
// a = |xc[j+i+m-14]|.  B=64, T=16384, M=8, K=3. Weights real.
// 4 outputs/thread: amp window av[18], x window xv[11] shared across the 4 outputs;
// VALU per output stays at the 208-FMA algebraic minimum.

#define B_SZ 64
#define T_SZ 16384
#define CHUNK 1024
#define HALO 14               // 2*(M-1)
#define WIN (CHUNK + HALO)    // 1038

__global__ __launch_bounds__(256) void gmp_kernel(const float* __restrict__ x,
                                                  const float* __restrict__ W,
                                                  float* __restrict__ out) {
    __shared__ float2 xs[WIN];   // xc window
    __shared__ float  as[WIN];   // |xc| window
    const int tid   = threadIdx.x;
    const int chunk = blockIdx.x & 15;   // T/CHUNK = 16 chunks per row
    const int b     = blockIdx.x >> 4;
    const int j0    = chunk * CHUNK;

    // Stage window [j0-14, j0+1024) of row b; zero-pad g<0.
    for (int q = tid; q < WIN; q += 256) {
        const int g = j0 - HALO + q;
        float2 v = make_float2(0.f, 0.f);
        if (g >= 0) v = ((const float2*)x)[(size_t)b * T_SZ + g];
        xs[q] = v;
        as[q] = sqrtf(fmaf(v.x, v.x, v.y * v.y));
    }
    __syncthreads();

    // Each thread: outputs j = j0 + 4*tid + {0,1,2,3}.
    const int t4 = 4 * tid;
    float av[18];
#pragma unroll
    for (int k = 0; k < 18; ++k) av[k] = as[t4 + k];      // 16B-aligned -> b128 reads
    float2 xv[11];
#pragma unroll
    for (int k = 0; k < 11; ++k) xv[k] = xs[t4 + 7 + k];

    float ar[4] = {0.f, 0.f, 0.f, 0.f};
    float ai[4] = {0.f, 0.f, 0.f, 0.f};
#pragma unroll
    for (int i = 0; i < 8; ++i) {
        float c[4];
        const float w0 = W[i * 25];
        c[0] = w0; c[1] = w0; c[2] = w0; c[3] = w0;
#pragma unroll
        for (int m = 0; m < 8; ++m) {
            const float w1 = W[i * 25 + 1 + m * 3];
            const float w2 = W[i * 25 + 2 + m * 3];
            const float w3 = W[i * 25 + 3 + m * 3];
#pragma unroll
            for (int r = 0; r < 4; ++r) {
                const float a = av[i + m + r];
                float h = fmaf(a, w3, w2);
                h = fmaf(a, h, w1);
                c[r] = fmaf(a, h, c[r]);
            }
        }
#pragma unroll
        for (int r = 0; r < 4; ++r) {
            ar[r] = fmaf(xv[i + r].x, c[r], ar[r]);
            ai[r] = fmaf(xv[i + r].y, c[r], ai[r]);
        }
    }

    // Four consecutive complex outputs -> two 16B stores.
    float4* op = (float4*)&out[2 * ((size_t)b * T_SZ + j0 + t4)];
    op[0] = make_float4(ar[0], ai[0], ar[1], ai[1]);
    op[1] = make_float4(ar[2], ai[2], ar[3], ai[3]);
}

extern "C" void kernel_launch(void* const* d_in, const int* in_sizes, int n_in,
                              void* d_out, int out_size, void* d_ws, size_t ws_size,
                              hipStream_t stream) {
    const float* x = (const float*)d_in[0];
    // d_in[1] is h_0 (unused)
    const float* W = (const float*)d_in[2];
    float* out = (float*)d_out;
    const int grid = B_SZ * (T_SZ / CHUNK);  // 1024 blocks
    gmp_kernel<<<dim3(grid), dim3(256), 0, stream>>>(x, W, out);
}